// Round 12
// baseline (466.647 us; speedup 1.0000x reference)
//
#include <hip/hip_runtime.h>

#define M_DIM 16384
#define N_DIM 4096
#define K_DIM 4096
#define NT 32            // K_DIM / BK, BK = 128 bytes (int8)

typedef __attribute__((ext_vector_type(4))) float f32x4;
typedef __attribute__((ext_vector_type(8))) short bf16x8;
typedef __attribute__((ext_vector_type(4))) int   i32x4;

__device__ __forceinline__ short f2bf(float f) {
    unsigned int u = __builtin_bit_cast(unsigned int, f);
    u += 0x7FFFu + ((u >> 16) & 1u);
    return (short)(u >> 16);
}

// ---- merged preprocessing: blocks [0,16384) quantize x rows; rest pack w ----
__global__ __launch_bounds__(256)
void quant_kernel(const float* __restrict__ x, const int* __restrict__ q,
                  char* __restrict__ x8, char* __restrict__ w8,
                  float* __restrict__ rs) {
    const int tid = threadIdx.x;
    if (blockIdx.x < M_DIM) {
        const int row = blockIdx.x;
        const float* xr = x + (size_t)row * K_DIM;
        f32x4 v[4];
        float am = 0.f;
#pragma unroll
        for (int p = 0; p < 4; ++p) {
            v[p] = *(const f32x4*)(xr + p * 1024 + tid * 4);
#pragma unroll
            for (int e = 0; e < 4; ++e) am = fmaxf(am, fabsf(v[p][e]));
        }
#pragma unroll
        for (int off = 32; off >= 1; off >>= 1)
            am = fmaxf(am, __shfl_xor(am, off, 64));
        __shared__ float smax[4];
        if ((tid & 63) == 0) smax[tid >> 6] = am;
        __syncthreads();
        am = fmaxf(fmaxf(smax[0], smax[1]), fmaxf(smax[2], smax[3]));
        const float inv = am > 0.f ? 127.f / am : 0.f;
        if (tid == 0) rs[row] = am / 127.f;
        int* o32 = (int*)(x8 + (size_t)row * K_DIM);
#pragma unroll
        for (int p = 0; p < 4; ++p) {
            const int b0 = (int)rintf(v[p][0] * inv);
            const int b1 = (int)rintf(v[p][1] * inv);
            const int b2 = (int)rintf(v[p][2] * inv);
            const int b3 = (int)rintf(v[p][3] * inv);
            o32[p * 256 + tid] = (b0 & 255) | ((b1 & 255) << 8) | ((b2 & 255) << 16) | ((b3 & 255) << 24);
        }
    } else {
        const long n = (long)N_DIM * K_DIM;
        long i = ((long)(blockIdx.x - M_DIM) * 256 + tid) * 16;
        const long stride = 2048L * 256 * 16;
        for (; i < n; i += stride) {
            i32x4 o;
#pragma unroll
            for (int j = 0; j < 4; ++j) {
                i32x4 a = *(const i32x4*)(q + i + j * 4);
                o[j] = (a[0] & 255) | ((a[1] & 255) << 8) | ((a[2] & 255) << 16) | ((a[3] & 255) << 24);
            }
            *(i32x4*)(w8 + i) = o;
        }
    }
}

__device__ __forceinline__ void load_lds16(const void* g, void* l) {
    __builtin_amdgcn_global_load_lds((const __attribute__((address_space(1))) void*)g,
                                     (__attribute__((address_space(3))) void*)l, 16, 0, 0);
}

#define BAR() __builtin_amdgcn_s_barrier()
#define VM(n) asm volatile("s_waitcnt vmcnt(" #n ")" ::: "memory")
#define SETP1 __builtin_amdgcn_s_setprio(1)
#define SETP0 __builtin_amdgcn_s_setprio(0)

// ============ 128x128-tile int8 GEMM, 2 blocks/CU (cross-block overlap) ============
// 256 threads / 4 waves (wm=w>>1, wn=w&1; per-wave 64x64 output, acc = 64 VGPR).
// LDS 64 KiB: lds[buf][A|B][128 rows x 128 B], verified read microstructure
// (16-row groups, 8 slots, slot ^= row&7 via pre-swizzled global source).
// Per K-tile t: 4 phases P(ih,jh) = {frag reads; stage 1 unit (2 loads); VM(4);
// BAR; 8 MFMA; BAR}. Units (half-regions, row-contiguous runs): staged t -> t+1:
// P1:B-jh0, P2:A-ih0, P3:B-jh1, P4:A-ih1. Ledger: every unit staged >=3 phases
// before its read; >=2 barriers between read-issue and overwrite-stage; VM(4)
// forces the unit needed next phase (2 loads/unit, 3 units in flight).
__global__ __launch_bounds__(256, 2)
void gemm2b_i8(const char* __restrict__ A, const char* __restrict__ Bw,
               const float* __restrict__ rs, const float* __restrict__ scales,
               const float* __restrict__ bias, float* __restrict__ out) {
    __shared__ char lds[2][2][128 * 128];   // 64 KiB -> 2 blocks/CU

    const int tid  = threadIdx.x;
    const int lane = tid & 63;
    const int w    = tid >> 6;     // 0..3
    const int wm   = w >> 1;
    const int wn   = w & 1;
    const int lrow = lane & 15;
    const int lkg  = lane >> 4;
    const int sx   = lane & 7;

    const int nwg = gridDim.x;     // 4096, %8==0
    const int swz = ((int)blockIdx.x & 7) * (nwg >> 3) + ((int)blockIdx.x >> 3);
    const int bn  = (swz & 31) << 7;    // 32 n-tiles
    const int bm  = (swz >> 5) << 7;    // 128 m-tiles

    // staging geometry: unit h (half-region), load L: chunk c = h*256+L*512+tid
    // row = c>>3, slot = c&7, global k-chunk kc = slot ^ (row&7); lds byte = c*16.
    long gOff[2][2];
#pragma unroll
    for (int h = 0; h < 2; ++h)
#pragma unroll
        for (int L = 0; L < 2; ++L) {
            const int c   = h * 256 + L * 512 + tid;
            const int row = c >> 3;
            const int kc  = (c & 7) ^ (row & 7);
            gOff[h][L] = (long)row * K_DIM + kc * 16;
        }
    const char* aB = A  + (size_t)bm * K_DIM;
    const char* bB = Bw + (size_t)bn * K_DIM;

#define STAGE(reg, buf, h, kt) do { \
    const char* gb = (reg) ? bB : aB; \
    load_lds16(gb + gOff[h][0] + (long)(kt) * 128, \
               &lds[buf][reg][((h) << 12) + (w << 10)]); \
    load_lds16(gb + gOff[h][1] + (long)(kt) * 128, \
               &lds[buf][reg][((h) << 12) + 8192 + (w << 10)]); \
} while (0)

#define RD_A(buf, sub, ks) \
    (*(const i32x4*)&lds[buf][0][(((wm << 6) + (sub) * 16 + lrow) << 7) + (((((ks) << 2) + lkg) ^ sx) << 4)])
#define RD_B(buf, jj, ks) \
    (*(const i32x4*)&lds[buf][1][(((wn << 6) + (jj) * 16 + lrow) << 7) + (((((ks) << 2) + lkg) ^ sx) << 4)])

    i32x4 acc[4][4];
#pragma unroll
    for (int i = 0; i < 4; ++i)
#pragma unroll
        for (int j = 0; j < 4; ++j)
            acc[i][j] = (i32x4){0, 0, 0, 0};

    i32x4 aFa[2][2], aFb[2][2], bFa[2][2], bFb[2][2];

#define MMA4(I0, J0, AF, BF) do { \
    SETP1; \
    _Pragma("unroll") for (int s = 0; s < 2; ++s) \
    _Pragma("unroll") for (int j = 0; j < 2; ++j) \
    _Pragma("unroll") for (int k = 0; k < 2; ++k) \
        acc[(I0) + s][(J0) + j] = __builtin_amdgcn_mfma_i32_16x16x64_i8( \
            AF[s][k], BF[j][k], acc[(I0) + s][(J0) + j], 0, 0, 0); \
    SETP0; \
} while (0)

    // prologue: tile0 units in ledger order B0,A0,B1,A1; force B0,A0.
    STAGE(1, 0, 0, 0); STAGE(0, 0, 0, 0); STAGE(1, 0, 1, 0); STAGE(0, 0, 1, 0);
    VM(4);
    BAR();

    for (int t = 0; t < NT; ++t) {
        const int buf = t & 1, nb = buf ^ 1;
        const bool st = (t + 1 < NT);

        // P1 (ih0 x jh0): read aFa, bFa; stage B-jh0(t+1)
#pragma unroll
        for (int k = 0; k < 2; ++k) {
            aFa[0][k] = RD_A(buf, 0, k); aFa[1][k] = RD_A(buf, 1, k);
            bFa[0][k] = RD_B(buf, 0, k); bFa[1][k] = RD_B(buf, 1, k);
        }
        if (st) STAGE(1, nb, 0, t + 1);
        if (st) { VM(4); } else { VM(2); }
        BAR(); MMA4(0, 0, aFa, bFa); BAR();

        // P2 (ih0 x jh1): read bFb; stage A-ih0(t+1)
#pragma unroll
        for (int k = 0; k < 2; ++k) {
            bFb[0][k] = RD_B(buf, 2, k); bFb[1][k] = RD_B(buf, 3, k);
        }
        if (st) STAGE(0, nb, 0, t + 1);
        if (st) { VM(4); } else { VM(0); }
        BAR(); MMA4(0, 2, aFa, bFb); BAR();

        // P3 (ih1 x jh0): read aFb; stage B-jh1(t+1)
#pragma unroll
        for (int k = 0; k < 2; ++k) {
            aFb[0][k] = RD_A(buf, 2, k); aFb[1][k] = RD_A(buf, 3, k);
        }
        if (st) { STAGE(1, nb, 1, t + 1); VM(4); }
        BAR(); MMA4(2, 0, aFb, bFa); BAR();

        // P4 (ih1 x jh1): stage A-ih1(t+1)
        if (st) { STAGE(0, nb, 1, t + 1); VM(4); }
        BAR(); MMA4(2, 2, aFb, bFb); BAR();
    }

    // epilogue: y = idot * (rs[row]*scales[col]) + bias[col]
#pragma unroll
    for (int i = 0; i < 4; ++i) {
        const int r0 = bm + (wm << 6) + i * 16 + (lkg << 2);
        const f32x4 rsv = *(const f32x4*)&rs[r0];
#pragma unroll
        for (int j = 0; j < 4; ++j) {
            const int col = bn + (wn << 6) + j * 16 + lrow;
            const float sc = scales[col];
            const float bb = bias[col];
#pragma unroll
            for (int r = 0; r < 4; ++r)
                out[(size_t)(r0 + r) * N_DIM + col] = (float)acc[i][j][r] * (rsv[r] * sc) + bb;
        }
    }
#undef STAGE
#undef RD_A
#undef RD_B
#undef MMA4
}

// ============ fallback (ws too small): reg-staged bf16, known-correct ============
__global__ __launch_bounds__(256)
void gemm_fallback(const float* __restrict__ Xf, const int* __restrict__ Qw,
                   const float* __restrict__ scales, const float* __restrict__ bias,
                   float* __restrict__ out) {
    __shared__ short a_lds[128 * 64];
    __shared__ short b_lds[128 * 64];
    const int tid  = threadIdx.x;
    const int lane = tid & 63;
    const int wid  = tid >> 6;
    const int wm   = wid >> 1;
    const int wn   = wid & 1;
    const int bn = (blockIdx.x % (N_DIM / 128)) * 128;
    const int bm = (blockIdx.x / (N_DIM / 128)) * 128;
    const int lrow = lane & 15;
    const int lkg  = lane >> 4;

    f32x4 acc[4][4];
#pragma unroll
    for (int i = 0; i < 4; ++i)
#pragma unroll
        for (int j = 0; j < 4; ++j)
            acc[i][j] = (f32x4){0.f, 0.f, 0.f, 0.f};

    for (int k0 = 0; k0 < K_DIM; k0 += 64) {
#pragma unroll
        for (int t = 0; t < 4; ++t) {
            const int ch  = t * 256 + tid;
            const int row = ch >> 3;
            const int kc  = (ch & 7) ^ (row & 7);
            {
                const float* sa = Xf + (size_t)(bm + row) * K_DIM + k0 + kc * 8;
                f32x4 a0 = *(const f32x4*)sa;
                f32x4 a1 = *(const f32x4*)(sa + 4);
                bf16x8 r;
                r[0] = f2bf(a0[0]); r[1] = f2bf(a0[1]); r[2] = f2bf(a0[2]); r[3] = f2bf(a0[3]);
                r[4] = f2bf(a1[0]); r[5] = f2bf(a1[1]); r[6] = f2bf(a1[2]); r[7] = f2bf(a1[3]);
                *(bf16x8*)&a_lds[ch * 8] = r;
            }
            {
                const int* sb = Qw + (size_t)(bn + row) * K_DIM + k0 + kc * 8;
                i32x4 q0 = *(const i32x4*)sb;
                i32x4 q1 = *(const i32x4*)(sb + 4);
                bf16x8 r;
                r[0] = f2bf((float)q0[0]); r[1] = f2bf((float)q0[1]);
                r[2] = f2bf((float)q0[2]); r[3] = f2bf((float)q0[3]);
                r[4] = f2bf((float)q1[0]); r[5] = f2bf((float)q1[1]);
                r[6] = f2bf((float)q1[2]); r[7] = f2bf((float)q1[3]);
                *(bf16x8*)&b_lds[ch * 8] = r;
            }
        }
        __syncthreads();
#pragma unroll
        for (int ks = 0; ks < 2; ++ks) {
            const int kgl = ks * 4 + lkg;
            bf16x8 af[4], bfr[4];
#pragma unroll
            for (int i = 0; i < 4; ++i) {
                const int am = wm * 64 + i * 16 + lrow;
                af[i]  = *(const bf16x8*)&a_lds[am * 64 + ((kgl ^ (am & 7)) << 3)];
                const int bnn = wn * 64 + i * 16 + lrow;
                bfr[i] = *(const bf16x8*)&b_lds[bnn * 64 + ((kgl ^ (bnn & 7)) << 3)];
            }
#pragma unroll
            for (int i = 0; i < 4; ++i)
#pragma unroll
                for (int j = 0; j < 4; ++j)
                    acc[i][j] = __builtin_amdgcn_mfma_f32_16x16x32_bf16(af[i], bfr[j], acc[i][j], 0, 0, 0);
        }
        __syncthreads();
    }
#pragma unroll
    for (int j = 0; j < 4; ++j) {
        const int col = bn + wn * 64 + j * 16 + lrow;
        const float s  = scales[col];
        const float bb = bias[col];
#pragma unroll
        for (int i = 0; i < 4; ++i) {
            const int row0 = bm + wm * 64 + i * 16 + lkg * 4;
#pragma unroll
            for (int r = 0; r < 4; ++r)
                out[(size_t)(row0 + r) * N_DIM + col] = acc[i][j][r] * s + bb;
        }
    }
}

extern "C" void kernel_launch(void* const* d_in, const int* in_sizes, int n_in,
                              void* d_out, int out_size, void* d_ws, size_t ws_size,
                              hipStream_t stream) {
    const float* x      = (const float*)d_in[0];
    const int*   qw     = (const int*)d_in[1];
    const float* scales = (const float*)d_in[2];
    const float* bias   = (const float*)d_in[3];
    float* out = (float*)d_out;

    const size_t x_elems = (size_t)M_DIM * K_DIM;
    const size_t w_elems = (size_t)N_DIM * K_DIM;
    const size_t need    = x_elems + w_elems + M_DIM * sizeof(float);

    if (ws_size >= need) {
        char*  x8 = (char*)d_ws;
        char*  w8 = x8 + x_elems;
        float* rs = (float*)(w8 + w_elems);
        quant_kernel<<<M_DIM + 2048, 256, 0, stream>>>(x, qw, x8, w8, rs);
        const dim3 grid((M_DIM / 128) * (N_DIM / 128));   // 4096 blocks
        gemm2b_i8<<<grid, 256, 0, stream>>>(x8, w8, rs, scales, bias, out);
    } else {
        const dim3 grid((M_DIM / 128) * (N_DIM / 128));
        gemm_fallback<<<grid, 256, 0, stream>>>(x, qw, scales, bias, out);
    }
}

// Round 13
// 342.776 us; speedup vs baseline: 1.3614x; 1.3614x over previous
//
#include <hip/hip_runtime.h>

#define M_DIM 16384
#define N_DIM 4096
#define K_DIM 4096
#define NT 32            // K_DIM / BK, BK = 128 bytes (int8)

typedef __attribute__((ext_vector_type(4))) float f32x4;
typedef __attribute__((ext_vector_type(8))) short bf16x8;
typedef __attribute__((ext_vector_type(4))) int   i32x4;

__device__ __forceinline__ short f2bf(float f) {
    unsigned int u = __builtin_bit_cast(unsigned int, f);
    u += 0x7FFFu + ((u >> 16) & 1u);
    return (short)(u >> 16);
}

// ---- merged preprocessing: blocks [0,16384) quantize x rows; rest pack w ----
__global__ __launch_bounds__(256)
void quant_kernel(const float* __restrict__ x, const int* __restrict__ q,
                  char* __restrict__ x8, char* __restrict__ w8,
                  float* __restrict__ rs) {
    const int tid = threadIdx.x;
    if (blockIdx.x < M_DIM) {
        const int row = blockIdx.x;
        const float* xr = x + (size_t)row * K_DIM;
        f32x4 v[4];
        float am = 0.f;
#pragma unroll
        for (int p = 0; p < 4; ++p) {
            v[p] = *(const f32x4*)(xr + p * 1024 + tid * 4);
#pragma unroll
            for (int e = 0; e < 4; ++e) am = fmaxf(am, fabsf(v[p][e]));
        }
#pragma unroll
        for (int off = 32; off >= 1; off >>= 1)
            am = fmaxf(am, __shfl_xor(am, off, 64));
        __shared__ float smax[4];
        if ((tid & 63) == 0) smax[tid >> 6] = am;
        __syncthreads();
        am = fmaxf(fmaxf(smax[0], smax[1]), fmaxf(smax[2], smax[3]));
        const float inv = am > 0.f ? 127.f / am : 0.f;
        if (tid == 0) rs[row] = am / 127.f;
        int* o32 = (int*)(x8 + (size_t)row * K_DIM);
#pragma unroll
        for (int p = 0; p < 4; ++p) {
            const int b0 = (int)rintf(v[p][0] * inv);
            const int b1 = (int)rintf(v[p][1] * inv);
            const int b2 = (int)rintf(v[p][2] * inv);
            const int b3 = (int)rintf(v[p][3] * inv);
            o32[p * 256 + tid] = (b0 & 255) | ((b1 & 255) << 8) | ((b2 & 255) << 16) | ((b3 & 255) << 24);
        }
    } else {
        const long n = (long)N_DIM * K_DIM;
        long i = ((long)(blockIdx.x - M_DIM) * 256 + tid) * 16;
        const long stride = 2048L * 256 * 16;
        for (; i < n; i += stride) {
            i32x4 o;
#pragma unroll
            for (int j = 0; j < 4; ++j) {
                i32x4 a = *(const i32x4*)(q + i + j * 4);
                o[j] = (a[0] & 255) | ((a[1] & 255) << 8) | ((a[2] & 255) << 16) | ((a[3] & 255) << 24);
            }
            *(i32x4*)(w8 + i) = o;
        }
    }
}

__device__ __forceinline__ void load_lds16(const void* g, void* l) {
    __builtin_amdgcn_global_load_lds((const __attribute__((address_space(1))) void*)g,
                                     (__attribute__((address_space(3))) void*)l, 16, 0, 0);
}

#define BAR() __builtin_amdgcn_s_barrier()
#define VM(n) asm volatile("s_waitcnt vmcnt(" #n ")" ::: "memory")

// ============ 256x256 8-phase int8 GEMM, 16x16x64 MFMA (R7 verbatim) ============
// Best measured configuration: GEMM ~287-290us, MfmaUtil ~43%, 0 bank conflicts.
// LDS regions (128B rows, 8x16B slots, slot ^= row&7 via pre-swizzled source).
// Fragment reads: 16-row / 4-slot-group pattern (0 conflicts, R3/R5/R7).
// 32-row / 2-slot-group pattern banned (2.5e7 conflicts, R4/R6).
// Schedule experiments R8 (dep-graph) / R9 (persistent) / R10 (L2 mapping) /
// R12 (128^2 2-blk/CU) were all null or negative vs this structure.
__global__ __launch_bounds__(512, 2)
void gemm8p_i8(const char* __restrict__ A, const char* __restrict__ Bw,
               const float* __restrict__ rs, const float* __restrict__ scales,
               const float* __restrict__ bias, float* __restrict__ out) {
    __shared__ char lds[2][4][128 * 128];   // 128 KiB

    const int tid  = threadIdx.x;
    const int lane = tid & 63;
    const int w    = tid >> 6;
    const int wm   = w >> 2;
    const int wn   = w & 3;
    const int lrow = lane & 15;
    const int lkg  = lane >> 4;
    const int sx   = lane & 7;

    const int nwg = gridDim.x;
    const int swz = (blockIdx.x & 7) * (nwg >> 3) + (blockIdx.x >> 3);
    const int bn  = (swz & 15) * 256;
    const int bm  = (swz >> 4) * 256;

    const char* aS[2];
    const char* bS[2];
#pragma unroll
    for (int L = 0; L < 2; ++L) {
        const int c   = L * 512 + tid;
        const int row = c >> 3;
        const int kc  = (c & 7) ^ (row & 7);
        const int mA  = bm + ((row >> 6) << 7) + (row & 63);
        const int nB  = bn + ((row >> 5) << 6) + (row & 31);
        aS[L] = A  + (size_t)mA * K_DIM + kc * 16;
        bS[L] = Bw + (size_t)nB * K_DIM + kc * 16;
    }
    const int wofs = w << 10;   // wave byte base, L=0

#define STAGE_A(buf, q, kt) do { \
    char* d = &lds[buf][q][wofs]; \
    const long ko = (long)(kt) * 128 + (long)(q) * (64 * (long)K_DIM); \
    load_lds16(aS[0] + ko, d); \
    load_lds16(aS[1] + ko, d + 8192); \
} while (0)

#define STAGE_B(buf, nh, kt) do { \
    char* d = &lds[buf][2 + (nh)][wofs]; \
    const long ko = (long)(kt) * 128 + (long)(nh) * (32 * (long)K_DIM); \
    load_lds16(bS[0] + ko, d); \
    load_lds16(bS[1] + ko, d + 8192); \
} while (0)

    const int aoff = (wm << 6) + lrow;
    const int boff = (wn << 5) + lrow;

#define RD_A(buf, q, sub, ks) \
    (*(const i32x4*)&lds[buf][q][((aoff + (sub) * 16) << 7) + (((((ks) << 2) + lkg) ^ sx) << 4)])
#define RD_B(buf, nh, sub, ks) \
    (*(const i32x4*)&lds[buf][2 + (nh)][((boff + (sub) * 16) << 7) + (((((ks) << 2) + lkg) ^ sx) << 4)])

    i32x4 acc[8][4];
#pragma unroll
    for (int i = 0; i < 8; ++i)
#pragma unroll
        for (int j = 0; j < 4; ++j)
            acc[i][j] = (i32x4){0, 0, 0, 0};

    i32x4 aF[4][2], bF0[2][2], bF1[2][2];

#define LOAD_AF(buf, q) do { \
    _Pragma("unroll") for (int ii = 0; ii < 4; ++ii) { \
        aF[ii][0] = RD_A(buf, q, ii, 0); aF[ii][1] = RD_A(buf, q, ii, 1); } \
} while (0)
#define LOAD_BF(dst, buf, nh) do { \
    _Pragma("unroll") for (int jj = 0; jj < 2; ++jj) { \
        dst[jj][0] = RD_B(buf, nh, jj, 0); dst[jj][1] = RD_B(buf, nh, jj, 1); } \
} while (0)
#define MMA_Q(mh, nh, BREG) do { \
    __builtin_amdgcn_s_setprio(1); \
    _Pragma("unroll") for (int ii = 0; ii < 4; ++ii) \
    _Pragma("unroll") for (int jj = 0; jj < 2; ++jj) \
    _Pragma("unroll") for (int ks = 0; ks < 2; ++ks) \
        acc[(mh) * 4 + ii][(nh) * 2 + jj] = __builtin_amdgcn_mfma_i32_16x16x64_i8( \
            aF[ii][ks], BREG[jj][ks], acc[(mh) * 4 + ii][(nh) * 2 + jj], 0, 0, 0); \
    __builtin_amdgcn_s_setprio(0); \
} while (0)

    // prologue: tile0 -> buf0 (4 ht), tile1 -> buf1 (first 3 ht)
    STAGE_A(0, 0, 0); STAGE_A(0, 1, 0); STAGE_B(0, 0, 0); STAGE_B(0, 1, 0);
    STAGE_A(1, 0, 1); STAGE_B(1, 0, 1); STAGE_B(1, 1, 1);
    VM(6);
    BAR();

    for (int it = 0; it < NT / 2; ++it) {
        const int kt  = it * 2;
        const bool s2 = (kt + 2 < NT);
        const bool s3 = (kt + 3 < NT);

        // P1
        LOAD_AF(0, 0); LOAD_BF(bF0, 0, 0);
        STAGE_A(1, 1, kt + 1);
        BAR(); MMA_Q(0, 0, bF0); BAR();
        // P2
        LOAD_BF(bF1, 0, 1);
        if (s2) STAGE_A(0, 0, kt + 2);
        BAR(); MMA_Q(0, 1, bF1); BAR();
        // P3
        LOAD_AF(0, 1);
        if (s2) STAGE_B(0, 0, kt + 2);
        BAR(); MMA_Q(1, 0, bF0); BAR();
        // P4
        if (s2) { STAGE_B(0, 1, kt + 2); VM(6); } else { VM(0); }
        BAR(); MMA_Q(1, 1, bF1); BAR();
        // P5
        LOAD_AF(1, 0); LOAD_BF(bF0, 1, 0);
        if (s2) STAGE_A(0, 1, kt + 2);
        BAR(); MMA_Q(0, 0, bF0); BAR();
        // P6
        LOAD_BF(bF1, 1, 1);
        if (s3) STAGE_A(1, 0, kt + 3);
        BAR(); MMA_Q(0, 1, bF1); BAR();
        // P7
        LOAD_AF(1, 1);
        if (s3) STAGE_B(1, 0, kt + 3);
        BAR(); MMA_Q(1, 0, bF0); BAR();
        // P8
        if (s3) { STAGE_B(1, 1, kt + 3); VM(6); }
        BAR(); MMA_Q(1, 1, bF1); BAR();
    }

    // epilogue: y = idot * (rs[row]*scales[col]) + bias[col]  (plain stores)
#pragma unroll
    for (int i = 0; i < 8; ++i) {
        const int r0 = bm + (wm << 7) + i * 16 + (lkg << 2);
        const f32x4 rsv = *(const f32x4*)&rs[r0];
#pragma unroll
        for (int j = 0; j < 4; ++j) {
            const int col = bn + (wn << 6) + j * 16 + lrow;
            const float sc = scales[col];
            const float bb = bias[col];
#pragma unroll
            for (int r = 0; r < 4; ++r)
                out[(size_t)(r0 + r) * N_DIM + col] = (float)acc[i][j][r] * (rsv[r] * sc) + bb;
        }
    }
#undef STAGE_A
#undef STAGE_B
#undef RD_A
#undef RD_B
#undef LOAD_AF
#undef LOAD_BF
#undef MMA_Q
}

// ============ fallback (ws too small): reg-staged bf16, known-correct ============
__global__ __launch_bounds__(256)
void gemm_fallback(const float* __restrict__ Xf, const int* __restrict__ Qw,
                   const float* __restrict__ scales, const float* __restrict__ bias,
                   float* __restrict__ out) {
    __shared__ short a_lds[128 * 64];
    __shared__ short b_lds[128 * 64];
    const int tid  = threadIdx.x;
    const int lane = tid & 63;
    const int wid  = tid >> 6;
    const int wm   = wid >> 1;
    const int wn   = wid & 1;
    const int bn = (blockIdx.x % (N_DIM / 128)) * 128;
    const int bm = (blockIdx.x / (N_DIM / 128)) * 128;
    const int lrow = lane & 15;
    const int lkg  = lane >> 4;

    f32x4 acc[4][4];
#pragma unroll
    for (int i = 0; i < 4; ++i)
#pragma unroll
        for (int j = 0; j < 4; ++j)
            acc[i][j] = (f32x4){0.f, 0.f, 0.f, 0.f};

    for (int k0 = 0; k0 < K_DIM; k0 += 64) {
#pragma unroll
        for (int t = 0; t < 4; ++t) {
            const int ch  = t * 256 + tid;
            const int row = ch >> 3;
            const int kc  = (ch & 7) ^ (row & 7);
            {
                const float* sa = Xf + (size_t)(bm + row) * K_DIM + k0 + kc * 8;
                f32x4 a0 = *(const f32x4*)sa;
                f32x4 a1 = *(const f32x4*)(sa + 4);
                bf16x8 r;
                r[0] = f2bf(a0[0]); r[1] = f2bf(a0[1]); r[2] = f2bf(a0[2]); r[3] = f2bf(a0[3]);
                r[4] = f2bf(a1[0]); r[5] = f2bf(a1[1]); r[6] = f2bf(a1[2]); r[7] = f2bf(a1[3]);
                *(bf16x8*)&a_lds[ch * 8] = r;
            }
            {
                const int* sb = Qw + (size_t)(bn + row) * K_DIM + k0 + kc * 8;
                i32x4 q0 = *(const i32x4*)sb;
                i32x4 q1 = *(const i32x4*)(sb + 4);
                bf16x8 r;
                r[0] = f2bf((float)q0[0]); r[1] = f2bf((float)q0[1]);
                r[2] = f2bf((float)q0[2]); r[3] = f2bf((float)q0[3]);
                r[4] = f2bf((float)q1[0]); r[5] = f2bf((float)q1[1]);
                r[6] = f2bf((float)q1[2]); r[7] = f2bf((float)q1[3]);
                *(bf16x8*)&b_lds[ch * 8] = r;
            }
        }
        __syncthreads();
#pragma unroll
        for (int ks = 0; ks < 2; ++ks) {
            const int kgl = ks * 4 + lkg;
            bf16x8 af[4], bfr[4];
#pragma unroll
            for (int i = 0; i < 4; ++i) {
                const int am = wm * 64 + i * 16 + lrow;
                af[i]  = *(const bf16x8*)&a_lds[am * 64 + ((kgl ^ (am & 7)) << 3)];
                const int bnn = wn * 64 + i * 16 + lrow;
                bfr[i] = *(const bf16x8*)&b_lds[bnn * 64 + ((kgl ^ (bnn & 7)) << 3)];
            }
#pragma unroll
            for (int i = 0; i < 4; ++i)
#pragma unroll
                for (int j = 0; j < 4; ++j)
                    acc[i][j] = __builtin_amdgcn_mfma_f32_16x16x32_bf16(af[i], bfr[j], acc[i][j], 0, 0, 0);
        }
        __syncthreads();
    }
#pragma unroll
    for (int j = 0; j < 4; ++j) {
        const int col = bn + wn * 64 + j * 16 + lrow;
        const float s  = scales[col];
        const float bb = bias[col];
#pragma unroll
        for (int i = 0; i < 4; ++i) {
            const int row0 = bm + wm * 64 + i * 16 + lkg * 4;
#pragma unroll
            for (int r = 0; r < 4; ++r)
                out[(size_t)(row0 + r) * N_DIM + col] = acc[i][j][r] * s + bb;
        }
    }
}

extern "C" void kernel_launch(void* const* d_in, const int* in_sizes, int n_in,
                              void* d_out, int out_size, void* d_ws, size_t ws_size,
                              hipStream_t stream) {
    const float* x      = (const float*)d_in[0];
    const int*   qw     = (const int*)d_in[1];
    const float* scales = (const float*)d_in[2];
    const float* bias   = (const float*)d_in[3];
    float* out = (float*)d_out;

    const size_t x_elems = (size_t)M_DIM * K_DIM;
    const size_t w_elems = (size_t)N_DIM * K_DIM;
    const size_t need    = x_elems + w_elems + M_DIM * sizeof(float);

    if (ws_size >= need) {
        char*  x8 = (char*)d_ws;
        char*  w8 = x8 + x_elems;
        float* rs = (float*)(w8 + w_elems);
        quant_kernel<<<M_DIM + 2048, 256, 0, stream>>>(x, qw, x8, w8, rs);
        const dim3 grid((M_DIM / 256) * (N_DIM / 256));   // 1024 blocks
        gemm8p_i8<<<grid, 512, 0, stream>>>(x8, w8, rs, scales, bias, out);
    } else {
        const dim3 grid((M_DIM / 128) * (N_DIM / 128));
        gemm_fallback<<<grid, 256, 0, stream>>>(x, qw, scales, bias, out);
    }
}